// Round 7
// baseline (226.878 us; speedup 1.0000x reference)
//
#include <hip/hip_runtime.h>
#include <hip/hip_bf16.h>
#include <cstdint>
#include <cstddef>

// out = (A2 @ E^T) @ W^T, A2[i,j] = a[i-j] lower-tri Toeplitz,
//   a[d] = (d/4096 + 1e-8)^0.2, a[0] = 1e-8^0.2
// gemm_a: T[i,e] = sum_{j<=i} a[i-j] * E[e,j]  (tri, split-j -> T0 + T1)
// tsum  : Tsum = T0 + T1
// gemm_b: out[i,v] = sum_e Tsum[i,e] * W[v,e]
//
// Round 7: NO LDS, NO barriers. Every MFMA fragment (lane ln -> row,
// quad -> 8 consecutive k) is a contiguous 16B global load: A of gemm_a
// comes from the Toeplitz replica table R (x = 4096+s-D0, s=ln&7; tm/kk
// are static immediate offsets), B from Eb rows, gemm_b operands from
// row-major Tsum/W. Register double-buffer with STATIC names (R5 lesson:
// dynamic indexing -> scratch). Loads for step s+2 issue after step-s
// MFMAs -> one full MFMA section covers L2 latency, per-wave, no sync.

#define L_SER 4096
#define DEMB  1024
#define DV    1024

#define R_STRIDE 4288   // per-replica length; max needed x+7 = 4262 < 4288
#define R_TOT    (8 * R_STRIDE)   // 34304 = 134 * 256 exactly
#define R_O0     4096

typedef __bf16 bf16_t;
typedef __attribute__((ext_vector_type(8))) __bf16 bf16x8;
typedef __attribute__((ext_vector_type(4))) float f32x4;

// ---------------------------------------------------------------------------
// Fused prep: blocks [0,134) build R; [134,2182) convert E; [2182,2694) convert W.
// ---------------------------------------------------------------------------
__global__ void prep_kernel(const float* __restrict__ E, const float* __restrict__ W,
                            bf16_t* __restrict__ Eb, bf16_t* __restrict__ Wb,
                            bf16_t* __restrict__ R) {
    const int b = blockIdx.x;
    if (b < 134) {                       // 134*256 = 34304 = R_TOT exact
        int idx = b * 256 + threadIdx.x;
        int s = idx / R_STRIDE;
        int x = idx - s * R_STRIDE;
        int d = R_O0 + s - x;
        float v = 0.0f;
        if (d >= 0 && d < L_SER)
            v = powf((d == 0) ? 1e-8f : ((float)d * (1.0f / (float)L_SER) + 1e-8f), 0.2f);
        R[idx] = (bf16_t)v;
    } else if (b < 134 + 2048) {         // E: 2048*256*8 = 4194304 elems exact
        int idx = (b - 134) * 256 + threadIdx.x;
        const f32x4* s = (const f32x4*)E;
        f32x4 v0 = s[idx * 2], v1 = s[idx * 2 + 1];
        bf16x8 o;
        o[0] = (bf16_t)v0[0]; o[1] = (bf16_t)v0[1]; o[2] = (bf16_t)v0[2]; o[3] = (bf16_t)v0[3];
        o[4] = (bf16_t)v1[0]; o[5] = (bf16_t)v1[1]; o[6] = (bf16_t)v1[2]; o[7] = (bf16_t)v1[3];
        ((bf16x8*)Eb)[idx] = o;
    } else {                             // W: 512*256*8 = 1048576 elems exact
        int idx = (b - 2182) * 256 + threadIdx.x;
        const f32x4* s = (const f32x4*)W;
        f32x4 v0 = s[idx * 2], v1 = s[idx * 2 + 1];
        bf16x8 o;
        o[0] = (bf16_t)v0[0]; o[1] = (bf16_t)v0[1]; o[2] = (bf16_t)v0[2]; o[3] = (bf16_t)v0[3];
        o[4] = (bf16_t)v1[0]; o[5] = (bf16_t)v1[1]; o[6] = (bf16_t)v1[2]; o[7] = (bf16_t)v1[3];
        ((bf16x8*)Wb)[idx] = o;
    }
}

// Tsum = T0 + T1 (bf16), 4M elems, 8/thread
__global__ void tsum_kernel(const bf16_t* __restrict__ T0, const bf16_t* __restrict__ T1,
                            bf16_t* __restrict__ Ts) {
    int idx = blockIdx.x * blockDim.x + threadIdx.x;   // < 524288
    bf16x8 a = ((const bf16x8*)T0)[idx];
    bf16x8 b = ((const bf16x8*)T1)[idx];
    bf16x8 o;
#pragma unroll
    for (int u = 0; u < 8; ++u) o[u] = (bf16_t)((float)a[u] + (float)b[u]);
    ((bf16x8*)Ts)[idx] = o;
}

// ---------------------------------------------------------------------------
// gemm_a: BM=128, BN=128, BK=64, split-j. 512 blocks (2/CU); pair (bid,bid+256)
// shares a CU -> per-CU work = (I+1)+(32-I) = 33 steps. 4 waves 2x2, wave tile
// 64x64 (4x4 MFMA), direct-fragment global loads, register double-buffer.
// ---------------------------------------------------------------------------
#define GA_LOAD(AF, BF, PA, PB)                                               \
    _Pragma("unroll")                                                         \
    for (int tm = 0; tm < 4; ++tm)                                            \
        _Pragma("unroll")                                                     \
        for (int kk = 0; kk < 2; ++kk)                                        \
            AF[tm * 2 + kk] = *(const bf16x8*)((PA) - 16 * tm + 32 * kk);     \
    (PA) += 128;                                                              \
    _Pragma("unroll")                                                         \
    for (int tn = 0; tn < 4; ++tn) {                                          \
        _Pragma("unroll")                                                     \
        for (int kk = 0; kk < 2; ++kk)                                        \
            BF[tn * 2 + kk] = *(const bf16x8*)((PB)[tn] + 32 * kk);           \
        (PB)[tn] += 128;                                                      \
    }

#define GA_MFMA(AF, BF)                                                       \
    _Pragma("unroll")                                                         \
    for (int kk = 0; kk < 2; ++kk)                                            \
        _Pragma("unroll")                                                     \
        for (int tm = 0; tm < 4; ++tm)                                        \
            _Pragma("unroll")                                                 \
            for (int tn = 0; tn < 4; ++tn)                                    \
                acc[tm][tn] = __builtin_amdgcn_mfma_f32_16x16x32_bf16(        \
                    AF[tm * 2 + kk], BF[tn * 2 + kk], acc[tm][tn], 0, 0, 0);

__global__ __launch_bounds__(256, 2) void gemm_a_kernel(const bf16_t* __restrict__ R,
                                                        const bf16_t* __restrict__ Eb,
                                                        bf16_t* __restrict__ T0,
                                                        bf16_t* __restrict__ T1) {
    const int bid = blockIdx.x;
    int I, nb, h;
    if (bid < 256) { I = bid >> 3;                nb = bid & 7;         h = 0; }
    else           { I = 31 - ((bid - 256) >> 3); nb = (bid - 256) & 7; h = 1; }
    const int i0 = I * 128;
    const int n0 = nb * 128;
    const int nsteps = I + 1;
    const int j0b = h ? 64 * (I + 1) : 0;
    bf16_t* __restrict__ Tout = h ? T1 : T0;

    const int tid  = threadIdx.x;
    const int wave = tid >> 6;
    const int lane = tid & 63;
    const int quad = lane >> 4;
    const int ln   = lane & 15;
    const int wm   = wave >> 1;
    const int wn   = wave & 1;

    f32x4 acc[4][4];
#pragma unroll
    for (int a = 0; a < 4; ++a)
#pragma unroll
        for (int b = 0; b < 4; ++b) acc[a][b] = (f32x4){0, 0, 0, 0};

    // A fragment base (tm=0, kk=0): R[s][x00], s=ln&7,
    //   x00 = R_O0 + s - (i0 + wm*64 + ln) + j0 + quad*8; x(tm,kk) = x00 -16tm +32kk
    const int s_rep = ln & 7;
    const bf16_t* paBase = R + (size_t)s_rep * R_STRIDE
                         + (R_O0 + s_rep - (i0 + wm * 64 + ln) + quad * 8);
    const bf16_t* pa0 = paBase + j0b;
    const bf16_t* pa1 = paBase + j0b + 64;
    const bf16_t* pb0[4];
    const bf16_t* pb1[4];
#pragma unroll
    for (int tn = 0; tn < 4; ++tn) {
        pb0[tn] = Eb + (size_t)(n0 + wn * 64 + tn * 16 + ln) * L_SER + j0b + quad * 8;
        pb1[tn] = pb0[tn] + 64;
    }

    bf16x8 afr0[8], bfr0[8], afr1[8], bfr1[8];
    GA_LOAD(afr0, bfr0, pa0, pb0)                        // step 0
    if (nsteps > 1) { GA_LOAD(afr1, bfr1, pa1, pb1) }    // step 1

    for (int s = 0;; s += 2) {
        GA_MFMA(afr0, bfr0)
        if (s + 2 < nsteps) { GA_LOAD(afr0, bfr0, pa0, pb0) }
        if (s + 1 >= nsteps) break;
        GA_MFMA(afr1, bfr1)
        if (s + 3 < nsteps) { GA_LOAD(afr1, bfr1, pa1, pb1) }
        if (s + 2 >= nsteps) break;
    }

    // C/D: col = ln (n), row = quad*4 + r (m89-verified)
#pragma unroll
    for (int tm = 0; tm < 4; ++tm) {
        int row_base = i0 + wm * 64 + tm * 16 + quad * 4;
#pragma unroll
        for (int tn = 0; tn < 4; ++tn) {
            int col = n0 + wn * 64 + tn * 16 + ln;
#pragma unroll
            for (int r = 0; r < 4; ++r)
                Tout[(size_t)(row_base + r) * DEMB + col] = (bf16_t)acc[tm][tn][r];
        }
    }
}

// ---------------------------------------------------------------------------
// gemm_b: out[i,v] = sum_e Tsum[i,e] * W[v,e]. BM=64, BN=128, BK=64, K=1024.
// 512 blocks (2/CU). 4 waves 2x2, wave tile 32x64 (2x4 MFMA), direct loads.
// ---------------------------------------------------------------------------
#define GB_LOAD(AF, BF, PA, PB)                                               \
    _Pragma("unroll")                                                         \
    for (int tm = 0; tm < 2; ++tm) {                                          \
        _Pragma("unroll")                                                     \
        for (int kk = 0; kk < 2; ++kk)                                        \
            AF[tm * 2 + kk] = *(const bf16x8*)((PA)[tm] + 32 * kk);           \
        (PA)[tm] += 128;                                                      \
    }                                                                         \
    _Pragma("unroll")                                                         \
    for (int tn = 0; tn < 4; ++tn) {                                          \
        _Pragma("unroll")                                                     \
        for (int kk = 0; kk < 2; ++kk)                                        \
            BF[tn * 2 + kk] = *(const bf16x8*)((PB)[tn] + 32 * kk);           \
        (PB)[tn] += 128;                                                      \
    }

#define GB_MFMA(AF, BF)                                                       \
    _Pragma("unroll")                                                         \
    for (int kk = 0; kk < 2; ++kk)                                            \
        _Pragma("unroll")                                                     \
        for (int tm = 0; tm < 2; ++tm)                                        \
            _Pragma("unroll")                                                 \
            for (int tn = 0; tn < 4; ++tn)                                    \
                acc[tm][tn] = __builtin_amdgcn_mfma_f32_16x16x32_bf16(        \
                    AF[tm * 2 + kk], BF[tn * 2 + kk], acc[tm][tn], 0, 0, 0);

__global__ __launch_bounds__(256, 2) void gemm_b_kernel(const bf16_t* __restrict__ Ts,
                                                        const bf16_t* __restrict__ Wb,
                                                        float* __restrict__ out) {
    const int bid = blockIdx.x;
    const int ib = bid >> 3;        // 0..63
    const int nb = bid & 7;
    const int i0 = ib * 64;
    const int n0 = nb * 128;

    const int tid  = threadIdx.x;
    const int wave = tid >> 6;
    const int lane = tid & 63;
    const int quad = lane >> 4;
    const int ln   = lane & 15;
    const int wm   = wave >> 1;     // 0..1 over 64 m (32 each)
    const int wn   = wave & 1;      // 0..1 over 128 n (64 each)

    f32x4 acc[2][4];
#pragma unroll
    for (int a = 0; a < 2; ++a)
#pragma unroll
        for (int b = 0; b < 4; ++b) acc[a][b] = (f32x4){0, 0, 0, 0};

    const int nsteps = DEMB / 64;   // 16 (even)

    const bf16_t* pa0[2];
    const bf16_t* pa1[2];
    const bf16_t* pb0[4];
    const bf16_t* pb1[4];
#pragma unroll
    for (int tm = 0; tm < 2; ++tm) {
        pa0[tm] = Ts + (size_t)(i0 + wm * 32 + tm * 16 + ln) * DEMB + quad * 8;
        pa1[tm] = pa0[tm] + 64;
    }
#pragma unroll
    for (int tn = 0; tn < 4; ++tn) {
        pb0[tn] = Wb + (size_t)(n0 + wn * 64 + tn * 16 + ln) * DEMB + quad * 8;
        pb1[tn] = pb0[tn] + 64;
    }

    bf16x8 afr0[4], bfr0[8], afr1[4], bfr1[8];
    GB_LOAD(afr0, bfr0, pa0, pb0)   // step 0
    GB_LOAD(afr1, bfr1, pa1, pb1)   // step 1

    for (int s = 0;; s += 2) {
        GB_MFMA(afr0, bfr0)
        if (s + 2 < nsteps) { GB_LOAD(afr0, bfr0, pa0, pb0) }
        GB_MFMA(afr1, bfr1)
        if (s + 3 < nsteps) { GB_LOAD(afr1, bfr1, pa1, pb1) }
        if (s + 2 >= nsteps) break;
    }

#pragma unroll
    for (int tm = 0; tm < 2; ++tm) {
        int row_base = i0 + wm * 32 + tm * 16 + quad * 4;
#pragma unroll
        for (int tn = 0; tn < 4; ++tn) {
            int col = n0 + wn * 64 + tn * 16 + ln;
#pragma unroll
            for (int r = 0; r < 4; ++r)
                out[(size_t)(row_base + r) * DV + col] = acc[tm][tn][r];
        }
    }
}

// ---------------------------------------------------------------------------
extern "C" void kernel_launch(void* const* d_in, const int* in_sizes, int n_in,
                              void* d_out, int out_size, void* d_ws, size_t ws_size,
                              hipStream_t stream) {
    const float* E = (const float*)d_in[0];   // (1024, 4096) f32
    const float* W = (const float*)d_in[1];   // (1024, 1024) f32
    float* out = (float*)d_out;               // (4096, 1024) f32

    char* ws = (char*)d_ws;
    bf16_t* Eb = (bf16_t*)(ws);                               // 8 MB
    bf16_t* T0 = (bf16_t*)(ws + (size_t)8  * 1024 * 1024);    // 8 MB
    bf16_t* T1 = (bf16_t*)(ws + (size_t)16 * 1024 * 1024);    // 8 MB
    bf16_t* Tsm= (bf16_t*)(ws + (size_t)24 * 1024 * 1024);    // 8 MB
    bf16_t* Wb = (bf16_t*)(ws + (size_t)32 * 1024 * 1024);    // 2 MB
    bf16_t* R  = (bf16_t*)(ws + (size_t)34 * 1024 * 1024);    // 68.6 KB

    prep_kernel<<<2694, 256, 0, stream>>>(E, W, Eb, Wb, R);
    gemm_a_kernel<<<512, 256, 0, stream>>>(R, Eb, T0, T1);
    tsum_kernel<<<2048, 256, 0, stream>>>(T0, T1, Tsm);
    gemm_b_kernel<<<512, 256, 0, stream>>>(Tsm, Wb, out);
}

// Round 8
// 149.099 us; speedup vs baseline: 1.5217x; 1.5217x over previous
//
#include <hip/hip_runtime.h>
#include <hip/hip_bf16.h>
#include <cstdint>
#include <cstddef>

// out = (A2 @ E^T) @ W^T, A2[i,j] = a[i-j] lower-tri Toeplitz,
//   a[d] = (d/4096 + 1e-8)^0.2, a[0] = 1e-8^0.2
// gemm_a: T[i,e] = sum_{j<=i} a[i-j] * E[e,j]  (tri, split-j -> T0 + T1)
// gemm_b: out[i,v] = sum_e (T0+T1)[i,e] * W[v,e]
//
// Round 8 (hybrid): R6 was LDS-bound (per block-step 96 KB LDS traffic vs
// 538 cy MFMA); R7 (all-direct) spilled 128 VGPRs of fragment buffers to
// scratch (WRITE_SIZE 165 MB). Hybrid: direct-load only the cache-hot
// operand (gemm_a A from 67KB L1-hot R table; gemm_b B from 2MB L2-hot Wb),
// keep the other operand on the R6 LDS ping-pong pipeline. LDS traffic
// halves -> balanced with MFMA; register demand stays under the (256,2) cap.

#define L_SER 4096
#define DEMB  1024
#define DV    1024

#define R_STRIDE 4288   // per-replica length (max x+7 = 4230 < 4288)
#define R_TOT    (8 * R_STRIDE)   // 34304 = 134 * 256 exactly
#define R_O0     4096
#define LDP      72     // padded LDS row (elems)

typedef __bf16 bf16_t;
typedef __attribute__((ext_vector_type(8))) __bf16 bf16x8;
typedef __attribute__((ext_vector_type(4))) float f32x4;

// ---------------------------------------------------------------------------
// Fused prep: blocks [0,134) build R; [134,2182) convert E; [2182,2694) convert W.
// ---------------------------------------------------------------------------
__global__ void prep_kernel(const float* __restrict__ E, const float* __restrict__ W,
                            bf16_t* __restrict__ Eb, bf16_t* __restrict__ Wb,
                            bf16_t* __restrict__ R) {
    const int b = blockIdx.x;
    if (b < 134) {
        int idx = b * 256 + threadIdx.x;
        int s = idx / R_STRIDE;
        int x = idx - s * R_STRIDE;
        int d = R_O0 + s - x;
        float v = 0.0f;
        if (d >= 0 && d < L_SER)
            v = powf((d == 0) ? 1e-8f : ((float)d * (1.0f / (float)L_SER) + 1e-8f), 0.2f);
        R[idx] = (bf16_t)v;
    } else if (b < 134 + 2048) {
        int idx = (b - 134) * 256 + threadIdx.x;
        const f32x4* s = (const f32x4*)E;
        f32x4 v0 = s[idx * 2], v1 = s[idx * 2 + 1];
        bf16x8 o;
        o[0] = (bf16_t)v0[0]; o[1] = (bf16_t)v0[1]; o[2] = (bf16_t)v0[2]; o[3] = (bf16_t)v0[3];
        o[4] = (bf16_t)v1[0]; o[5] = (bf16_t)v1[1]; o[6] = (bf16_t)v1[2]; o[7] = (bf16_t)v1[3];
        ((bf16x8*)Eb)[idx] = o;
    } else {
        int idx = (b - 2182) * 256 + threadIdx.x;
        const f32x4* s = (const f32x4*)W;
        f32x4 v0 = s[idx * 2], v1 = s[idx * 2 + 1];
        bf16x8 o;
        o[0] = (bf16_t)v0[0]; o[1] = (bf16_t)v0[1]; o[2] = (bf16_t)v0[2]; o[3] = (bf16_t)v0[3];
        o[4] = (bf16_t)v1[0]; o[5] = (bf16_t)v1[1]; o[6] = (bf16_t)v1[2]; o[7] = (bf16_t)v1[3];
        ((bf16x8*)Wb)[idx] = o;
    }
}

// ---------------------------------------------------------------------------
// gemm_a: BM=128, BN=128, BK=64, split-j. 512 blocks (2/CU), pair (bid,bid+256)
// shares a CU -> 33 steps per CU. 4 waves 2x2, wave tile 64x64 (4x4 MFMA).
// A: direct 16B loads from L1-hot R (proven mapping, R7). B: LDS ping-pong.
// ---------------------------------------------------------------------------
#define GA_BSTAGE(SBOFS, RB)                                                  \
    _Pragma("unroll")                                                         \
    for (int c = 0; c < 4; ++c)                                               \
        *(bf16x8*)&sB[(SBOFS) + (c * 32 + srow) * LDP + kc8] = RB[c];

#define GA_BPREFETCH(RB)                                                      \
    _Pragma("unroll")                                                         \
    for (int c = 0; c < 4; ++c) {                                             \
        RB[c] = *(const bf16x8*)pB[c];                                        \
        pB[c] += 64;                                                          \
    }

#define GA_ALOAD(PA)                                                          \
    _Pragma("unroll")                                                         \
    for (int tm = 0; tm < 4; ++tm)                                            \
        _Pragma("unroll")                                                     \
        for (int kk = 0; kk < 2; ++kk)                                        \
            afr[tm * 2 + kk] = *(const bf16x8*)((PA) - 16 * tm + 32 * kk);    \
    (PA) += 64;

#define GA_BREAD(SBOFS)                                                       \
    _Pragma("unroll")                                                         \
    for (int tn = 0; tn < 4; ++tn)                                            \
        _Pragma("unroll")                                                     \
        for (int kk = 0; kk < 2; ++kk)                                        \
            bfr[tn * 2 + kk] = *(const bf16x8*)&sB[(SBOFS) +                  \
                (wn * 64 + tn * 16 + ln) * LDP + kk * 32 + quad * 8];

#define GA_MFMA()                                                             \
    _Pragma("unroll")                                                         \
    for (int kk = 0; kk < 2; ++kk)                                            \
        _Pragma("unroll")                                                     \
        for (int tm = 0; tm < 4; ++tm)                                        \
            _Pragma("unroll")                                                 \
            for (int tn = 0; tn < 4; ++tn)                                    \
                acc[tm][tn] = __builtin_amdgcn_mfma_f32_16x16x32_bf16(        \
                    afr[tm * 2 + kk], bfr[tn * 2 + kk], acc[tm][tn], 0, 0, 0);

__global__ __launch_bounds__(256, 2) void gemm_a_kernel(const bf16_t* __restrict__ R,
                                                        const bf16_t* __restrict__ Eb,
                                                        bf16_t* __restrict__ T0,
                                                        bf16_t* __restrict__ T1) {
    __shared__ __align__(16) bf16_t sB[2 * 128 * LDP];   // 36 KB (B only)

    const int bid = blockIdx.x;
    int I, nb, h;
    if (bid < 256) { I = bid >> 3;                nb = bid & 7;         h = 0; }
    else           { I = 31 - ((bid - 256) >> 3); nb = (bid - 256) & 7; h = 1; }
    const int i0 = I * 128;
    const int n0 = nb * 128;
    const int nsteps = I + 1;
    const int j0b = h ? 64 * (I + 1) : 0;
    bf16_t* __restrict__ Tout = h ? T1 : T0;

    const int tid  = threadIdx.x;
    const int wave = tid >> 6;
    const int lane = tid & 63;
    const int quad = lane >> 4;
    const int ln   = lane & 15;
    const int wm   = wave >> 1;
    const int wn   = wave & 1;
    const int srow = tid >> 3;              // 0..31
    const int kc8  = (tid & 7) * 8;

    f32x4 acc[4][4];
#pragma unroll
    for (int a = 0; a < 4; ++a)
#pragma unroll
        for (int b = 0; b < 4; ++b) acc[a][b] = (f32x4){0, 0, 0, 0};

    // A direct-load base (R7-verified): s = ln&7,
    //   x(tm,kk,step) = R_O0 + s - (i0 + wm*64 + ln) + j0b + 64*step - 16*tm + 32*kk + quad*8
    const int s_rep = ln & 7;
    const bf16_t* pa = R + (size_t)s_rep * R_STRIDE
                     + (R_O0 + s_rep - (i0 + wm * 64 + ln) + j0b + quad * 8);

    const bf16_t* pB[4];
    bf16x8 rb0[4], rb1[4], afr[8], bfr[8];
#pragma unroll
    for (int c = 0; c < 4; ++c)
        pB[c] = Eb + (size_t)(n0 + c * 32 + srow) * L_SER + j0b + kc8;

    GA_BPREFETCH(rb0)                       // step 0
    if (nsteps > 1) { GA_BPREFETCH(rb1) }   // step 1

    for (int s = 0;; s += 2) {
        // ---- phase 0: step s (buffer 0) ----
        GA_BSTAGE(0, rb0)
        __syncthreads();
        if (s + 2 < nsteps) { GA_BPREFETCH(rb0) }
        GA_ALOAD(pa)
        GA_BREAD(0)
        GA_MFMA()
        if (s + 1 >= nsteps) break;
        // ---- phase 1: step s+1 (buffer 1) ----
        GA_BSTAGE(128 * LDP, rb1)
        __syncthreads();
        if (s + 3 < nsteps) { GA_BPREFETCH(rb1) }
        GA_ALOAD(pa)
        GA_BREAD(128 * LDP)
        GA_MFMA()
        if (s + 2 >= nsteps) break;
    }

    // C/D: col = ln (n), row = quad*4 + r (m89-verified)
#pragma unroll
    for (int tm = 0; tm < 4; ++tm) {
        int row_base = i0 + wm * 64 + tm * 16 + quad * 4;
#pragma unroll
        for (int tn = 0; tn < 4; ++tn) {
            int col = n0 + wn * 64 + tn * 16 + ln;
#pragma unroll
            for (int r = 0; r < 4; ++r)
                Tout[(size_t)(row_base + r) * DEMB + col] = (bf16_t)acc[tm][tn][r];
        }
    }
}

// ---------------------------------------------------------------------------
// gemm_b: out[i,v] = sum_e (T0+T1)[i,e] * W[v,e]. BM=64, BN=128, BK=64, K=1024.
// 512 blocks (2/CU). A = T0+T1 via LDS pipeline (add fused in prefetch);
// B direct from L2-resident Wb, one-step-ahead register prefetch (2 sets).
// ---------------------------------------------------------------------------
#define GB_ASTAGE(SBOFS, RA)                                                  \
    _Pragma("unroll")                                                         \
    for (int c = 0; c < 2; ++c)                                               \
        *(bf16x8*)&sA[(SBOFS) + (c * 32 + srow) * LDP + kc8] = RA[c];

#define GB_APREFETCH(RA)                                                      \
    _Pragma("unroll")                                                         \
    for (int c = 0; c < 2; ++c) {                                             \
        bf16x8 t0 = *(const bf16x8*)p0[c];                                    \
        bf16x8 t1 = *(const bf16x8*)p1[c];                                    \
        bf16x8 o;                                                             \
        _Pragma("unroll")                                                     \
        for (int u = 0; u < 8; ++u) o[u] = (bf16_t)((float)t0[u] + (float)t1[u]); \
        RA[c] = o;                                                            \
        p0[c] += 64; p1[c] += 64;                                             \
    }

#define GB_BPREFETCH(BF)                                                      \
    _Pragma("unroll")                                                         \
    for (int tn = 0; tn < 4; ++tn) {                                          \
        _Pragma("unroll")                                                     \
        for (int kk = 0; kk < 2; ++kk)                                        \
            BF[tn * 2 + kk] = *(const bf16x8*)(pW[tn] + 32 * kk);             \
        pW[tn] += 64;                                                         \
    }

#define GB_AREAD(SBOFS)                                                       \
    _Pragma("unroll")                                                         \
    for (int tm = 0; tm < 2; ++tm)                                            \
        _Pragma("unroll")                                                     \
        for (int kk = 0; kk < 2; ++kk)                                        \
            afr[tm * 2 + kk] = *(const bf16x8*)&sA[(SBOFS) +                  \
                (wm * 32 + tm * 16 + ln) * LDP + kk * 32 + quad * 8];

#define GB_MFMA(BF)                                                           \
    _Pragma("unroll")                                                         \
    for (int kk = 0; kk < 2; ++kk)                                            \
        _Pragma("unroll")                                                     \
        for (int tm = 0; tm < 2; ++tm)                                        \
            _Pragma("unroll")                                                 \
            for (int tn = 0; tn < 4; ++tn)                                    \
                acc[tm][tn] = __builtin_amdgcn_mfma_f32_16x16x32_bf16(        \
                    afr[tm * 2 + kk], BF[tn * 2 + kk], acc[tm][tn], 0, 0, 0);

__global__ __launch_bounds__(256, 2) void gemm_b_kernel(const bf16_t* __restrict__ T0,
                                                        const bf16_t* __restrict__ T1,
                                                        const bf16_t* __restrict__ Wb,
                                                        float* __restrict__ out) {
    __shared__ __align__(16) bf16_t sA[2 * 64 * LDP];    // 18 KB (A only)

    const int bid = blockIdx.x;
    const int ib = bid >> 3;        // 0..63
    const int nb = bid & 7;
    const int i0 = ib * 64;
    const int n0 = nb * 128;

    const int tid  = threadIdx.x;
    const int wave = tid >> 6;
    const int lane = tid & 63;
    const int quad = lane >> 4;
    const int ln   = lane & 15;
    const int wm   = wave >> 1;     // 0..1 over 64 m
    const int wn   = wave & 1;      // 0..1 over 128 n
    const int srow = tid >> 3;      // 0..31
    const int kc8  = (tid & 7) * 8;

    f32x4 acc[2][4];
#pragma unroll
    for (int a = 0; a < 2; ++a)
#pragma unroll
        for (int b = 0; b < 4; ++b) acc[a][b] = (f32x4){0, 0, 0, 0};

    const int nsteps = DEMB / 64;   // 16 (even)

    const bf16_t* p0[2];
    const bf16_t* p1[2];
    const bf16_t* pW[4];
    bf16x8 ra0[2], ra1[2], afr[4], bf0[8], bf1[8];
#pragma unroll
    for (int c = 0; c < 2; ++c) {
        size_t arow = (size_t)(i0 + c * 32 + srow) * DEMB + kc8;
        p0[c] = T0 + arow;
        p1[c] = T1 + arow;
    }
#pragma unroll
    for (int tn = 0; tn < 4; ++tn)
        pW[tn] = Wb + (size_t)(n0 + wn * 64 + tn * 16 + ln) * DEMB + quad * 8;

    GB_APREFETCH(ra0)   // step 0 A
    GB_APREFETCH(ra1)   // step 1 A
    GB_BPREFETCH(bf0)   // step 0 B
    GB_BPREFETCH(bf1)   // step 1 B

    for (int s = 0;; s += 2) {
        // ---- phase 0: step s ----
        GB_ASTAGE(0, ra0)
        __syncthreads();
        if (s + 2 < nsteps) { GB_APREFETCH(ra0) }
        GB_AREAD(0)
        GB_MFMA(bf0)
        if (s + 2 < nsteps) { GB_BPREFETCH(bf0) }
        // ---- phase 1: step s+1 (nsteps even) ----
        GB_ASTAGE(64 * LDP, ra1)
        __syncthreads();
        if (s + 3 < nsteps) { GB_APREFETCH(ra1) }
        GB_AREAD(64 * LDP)
        GB_MFMA(bf1)
        if (s + 3 < nsteps) { GB_BPREFETCH(bf1) }
        if (s + 2 >= nsteps) break;
    }

#pragma unroll
    for (int tm = 0; tm < 2; ++tm) {
        int row_base = i0 + wm * 32 + tm * 16 + quad * 4;
#pragma unroll
        for (int tn = 0; tn < 4; ++tn) {
            int col = n0 + wn * 64 + tn * 16 + ln;
#pragma unroll
            for (int r = 0; r < 4; ++r)
                out[(size_t)(row_base + r) * DV + col] = acc[tm][tn][r];
        }
    }
}

// ---------------------------------------------------------------------------
extern "C" void kernel_launch(void* const* d_in, const int* in_sizes, int n_in,
                              void* d_out, int out_size, void* d_ws, size_t ws_size,
                              hipStream_t stream) {
    const float* E = (const float*)d_in[0];   // (1024, 4096) f32
    const float* W = (const float*)d_in[1];   // (1024, 1024) f32
    float* out = (float*)d_out;               // (4096, 1024) f32

    char* ws = (char*)d_ws;
    bf16_t* Eb = (bf16_t*)(ws);                               // 8 MB
    bf16_t* T0 = (bf16_t*)(ws + (size_t)8  * 1024 * 1024);    // 8 MB
    bf16_t* T1 = (bf16_t*)(ws + (size_t)16 * 1024 * 1024);    // 8 MB
    bf16_t* Wb = (bf16_t*)(ws + (size_t)24 * 1024 * 1024);    // 2 MB
    bf16_t* R  = (bf16_t*)(ws + (size_t)26 * 1024 * 1024);    // 68.6 KB

    prep_kernel<<<2694, 256, 0, stream>>>(E, W, Eb, Wb, R);
    gemm_a_kernel<<<512, 256, 0, stream>>>(R, Eb, T0, T1);
    gemm_b_kernel<<<512, 256, 0, stream>>>(T0, T1, Wb, out);
}

// Round 11
// 145.320 us; speedup vs baseline: 1.5612x; 1.0260x over previous
//
#include <hip/hip_runtime.h>
#include <hip/hip_bf16.h>
#include <cstdint>
#include <cstddef>

// out = (A2 @ E^T) @ W^T, A2[i,j] = a[i-j] lower-tri Toeplitz,
//   a[d] = (d/4096 + 1e-8)^0.2, a[0] = 1e-8^0.2
// gemm_a: T[i,e] = sum_{j<=i} a[i-j] * E[e,j]  (tri, split-j x4 -> T0..T3)
// gemm_b: out[i,v] = sum_e (T0+T1+T2+T3)[i,e] * W[v,e]
//
// Round 11 = Round 10 with the K-range bug fixed: block-row I covers
// j in [0, 128*(I+1)) = 2*(I+1) BK-64 steps (R10 used I+1 -> half the
// triangle missing, absmax 124). Everything else unchanged:
// gemm_a m97 shape (single 32KB LDS buffer, global_load_lds width-16,
// 2 barriers/step, split-j x4, 1024 blocks big-I-first, ~3 resident/CU);
// gemm_b 64x64 tiles, 1024 blocks, launch_bounds(256,4) -> 4 resident/CU.

#define L_SER 4096
#define DEMB  1024
#define DV    1024

#define R_STRIDE 4288             // per-replica length; max x+7 = 4223 < 4288
#define R_TOT    (8 * R_STRIDE)   // 34304 = 134 * 256
#define R_O0     4096
#define LDP      72               // padded LDS row for gemm_b only

typedef __bf16 bf16_t;
typedef __attribute__((ext_vector_type(8))) __bf16 bf16x8;
typedef __attribute__((ext_vector_type(4))) float f32x4;

__device__ __forceinline__ void load_lds16(const void* g, void* l) {
    __builtin_amdgcn_global_load_lds(
        (const __attribute__((address_space(1))) void*)g,
        (__attribute__((address_space(3))) void*)l, 16, 0, 0);
}

// ---------------------------------------------------------------------------
// Fused prep: blocks [0,134) build R; [134,2182) convert E; [2182,2694) convert W.
// ---------------------------------------------------------------------------
__global__ void prep_kernel(const float* __restrict__ E, const float* __restrict__ W,
                            bf16_t* __restrict__ Eb, bf16_t* __restrict__ Wb,
                            bf16_t* __restrict__ R) {
    const int b = blockIdx.x;
    if (b < 134) {
        int idx = b * 256 + threadIdx.x;
        int s = idx / R_STRIDE;
        int x = idx - s * R_STRIDE;
        int d = R_O0 + s - x;
        float v = 0.0f;
        if (d >= 0 && d < L_SER)
            v = powf((d == 0) ? 1e-8f : ((float)d * (1.0f / (float)L_SER) + 1e-8f), 0.2f);
        R[idx] = (bf16_t)v;
    } else if (b < 134 + 2048) {
        int idx = (b - 134) * 256 + threadIdx.x;
        const f32x4* s = (const f32x4*)E;
        f32x4 v0 = s[idx * 2], v1 = s[idx * 2 + 1];
        bf16x8 o;
        o[0] = (bf16_t)v0[0]; o[1] = (bf16_t)v0[1]; o[2] = (bf16_t)v0[2]; o[3] = (bf16_t)v0[3];
        o[4] = (bf16_t)v1[0]; o[5] = (bf16_t)v1[1]; o[6] = (bf16_t)v1[2]; o[7] = (bf16_t)v1[3];
        ((bf16x8*)Eb)[idx] = o;
    } else {
        int idx = (b - 2182) * 256 + threadIdx.x;
        const f32x4* s = (const f32x4*)W;
        f32x4 v0 = s[idx * 2], v1 = s[idx * 2 + 1];
        bf16x8 o;
        o[0] = (bf16_t)v0[0]; o[1] = (bf16_t)v0[1]; o[2] = (bf16_t)v0[2]; o[3] = (bf16_t)v0[3];
        o[4] = (bf16_t)v1[0]; o[5] = (bf16_t)v1[1]; o[6] = (bf16_t)v1[2]; o[7] = (bf16_t)v1[3];
        ((bf16x8*)Wb)[idx] = o;
    }
}

// ---------------------------------------------------------------------------
// gemm_a: BM=128, BN=128, BK=64, split-j x4. 1024 blocks, big-I first.
// m97 structure: single LDS buffer (unpadded 64-elem rows, required by
// global_load_lds lane-linear dest), stage -> barrier -> compute -> barrier.
// 4 waves 2x2, wave tile 64x64 (4x4 MFMA), 32 MFMA/wave/step.
// ---------------------------------------------------------------------------
__global__ __launch_bounds__(256) void gemm_a_kernel(const bf16_t* __restrict__ R,
                                                     const bf16_t* __restrict__ Eb,
                                                     bf16_t* __restrict__ T0,
                                                     bf16_t* __restrict__ T1,
                                                     bf16_t* __restrict__ T2,
                                                     bf16_t* __restrict__ T3) {
    __shared__ __align__(16) bf16_t sA[128 * 64];   // 16 KB
    __shared__ __align__(16) bf16_t sB[128 * 64];   // 16 KB

    const int bid = blockIdx.x;          // 0..1023
    const int I   = 31 - (bid >> 5);     // biggest K first (near-LPT)
    const int sub = bid & 31;
    const int q   = sub >> 3;            // quarter 0..3
    const int nb  = sub & 7;
    const int i0 = I * 128;
    const int n0 = nb * 128;
    const int tot  = 2 * (I + 1);        // FIXED (R10 had I+1: half the triangle)
    const int base = tot >> 2, rem = tot & 3;
    const int nsteps = base + (q < rem ? 1 : 0);
    const int j0b = 64 * (q * base + (q < rem ? q : rem));
    bf16_t* __restrict__ Tout = (q == 0) ? T0 : (q == 1) ? T1 : (q == 2) ? T2 : T3;

    const int tid  = threadIdx.x;
    const int wave = tid >> 6;
    const int lane = tid & 63;
    const int quad = lane >> 4;
    const int ln   = lane & 15;
    const int wm   = wave >> 1;
    const int wn   = wave & 1;
    const int srow = tid >> 3;              // 0..31
    const int kc8  = (tid & 7) * 8;

    f32x4 acc[4][4];
#pragma unroll
    for (int a = 0; a < 4; ++a)
#pragma unroll
        for (int b = 0; b < 4; ++b) acc[a][b] = (f32x4){0, 0, 0, 0};

    // Staging sources. A row r: replica s=r&7, back-off 8*(r>>3):
    //   elem (r, col) at step j0 = R[s][R_O0 - (i0-j0) - 8*(r>>3) + col]
    const bf16_t* pA[4];
    const bf16_t* pB[4];
#pragma unroll
    for (int c = 0; c < 4; ++c) {
        int r = c * 32 + srow;
        pA[c] = R + (size_t)(r & 7) * R_STRIDE + (R_O0 - i0 + j0b - 8 * (r >> 3) + kc8);
        pB[c] = Eb + (size_t)(n0 + c * 32 + srow) * L_SER + j0b + kc8;
    }

    for (int s = 0; s < nsteps; ++s) {
        // stage: LDS dest per c is lane-linear: wave-uniform base + lane*16B
#pragma unroll
        for (int c = 0; c < 4; ++c) {
            load_lds16(pA[c], &sA[c * 2048 + tid * 8]);
            pA[c] += 64;
        }
#pragma unroll
        for (int c = 0; c < 4; ++c) {
            load_lds16(pB[c], &sB[c * 2048 + tid * 8]);
            pB[c] += 64;
        }
        __syncthreads();   // compiler drains vmcnt(0) here (m97 behavior)

#pragma unroll
        for (int kk = 0; kk < 2; ++kk) {
            bf16x8 afr[4], bfr[4];
#pragma unroll
            for (int tm = 0; tm < 4; ++tm)
                afr[tm] = *(const bf16x8*)&sA[(wm * 64 + tm * 16 + ln) * 64 + kk * 32 + quad * 8];
#pragma unroll
            for (int tn = 0; tn < 4; ++tn)
                bfr[tn] = *(const bf16x8*)&sB[(wn * 64 + tn * 16 + ln) * 64 + kk * 32 + quad * 8];
#pragma unroll
            for (int tm = 0; tm < 4; ++tm)
#pragma unroll
                for (int tn = 0; tn < 4; ++tn)
                    acc[tm][tn] = __builtin_amdgcn_mfma_f32_16x16x32_bf16(afr[tm], bfr[tn], acc[tm][tn], 0, 0, 0);
        }
        __syncthreads();
    }

    // C/D: col = ln, row = quad*4 + r (m89-verified). nsteps==0 writes zeros.
#pragma unroll
    for (int tm = 0; tm < 4; ++tm) {
        int row_base = i0 + wm * 64 + tm * 16 + quad * 4;
#pragma unroll
        for (int tn = 0; tn < 4; ++tn) {
            int col = n0 + wn * 64 + tn * 16 + ln;
#pragma unroll
            for (int r = 0; r < 4; ++r)
                Tout[(size_t)(row_base + r) * DEMB + col] = (bf16_t)acc[tm][tn][r];
        }
    }
}

// ---------------------------------------------------------------------------
// gemm_b: out[i,v] = sum_e (T0+..+T3)[i,e] * W[v,e]. BM=64, BN=64, BK=64.
// 1024 blocks, 4 resident/CU (LDS 36.8KB, VGPR<=128 via (256,4)).
// R6 static ping-pong + distance-2 prefetch; 4-way T-sum in A-prefetch.
// 4 waves 2x2, wave tile 32x32 (2x2 MFMA).
// ---------------------------------------------------------------------------
#define GB_STAGE(SBOFS, RA, RB)                                              \
    _Pragma("unroll")                                                        \
    for (int c = 0; c < 2; ++c) {                                            \
        *(bf16x8*)&sA[(SBOFS) + (c * 32 + srow) * LDP + kc8] = RA[c];        \
        *(bf16x8*)&sB[(SBOFS) + (c * 32 + srow) * LDP + kc8] = RB[c];        \
    }

#define GB_PREFETCH(RA, RB)                                                  \
    _Pragma("unroll")                                                        \
    for (int c = 0; c < 2; ++c) {                                            \
        bf16x8 t0 = *(const bf16x8*)p0[c];                                   \
        bf16x8 t1 = *(const bf16x8*)p1[c];                                   \
        bf16x8 t2 = *(const bf16x8*)p2[c];                                   \
        bf16x8 t3 = *(const bf16x8*)p3[c];                                   \
        bf16x8 o;                                                            \
        _Pragma("unroll")                                                    \
        for (int u = 0; u < 8; ++u)                                          \
            o[u] = (bf16_t)(((float)t0[u] + (float)t1[u]) +                  \
                            ((float)t2[u] + (float)t3[u]));                  \
        RA[c] = o;                                                           \
        p0[c] += 64; p1[c] += 64; p2[c] += 64; p3[c] += 64;                  \
    }                                                                        \
    _Pragma("unroll")                                                        \
    for (int c = 0; c < 2; ++c) {                                            \
        RB[c] = *(const bf16x8*)pW[c];                                       \
        pW[c] += 64;                                                         \
    }

#define GB_COMPUTE(SBOFS)                                                    \
    _Pragma("unroll")                                                        \
    for (int kk = 0; kk < 2; ++kk) {                                         \
        bf16x8 afr[2], bfr[2];                                               \
        _Pragma("unroll")                                                    \
        for (int tm = 0; tm < 2; ++tm)                                       \
            afr[tm] = *(const bf16x8*)&sA[(SBOFS) + (wm * 32 + tm * 16 + ln) * LDP + kk * 32 + quad * 8]; \
        _Pragma("unroll")                                                    \
        for (int tn = 0; tn < 2; ++tn)                                       \
            bfr[tn] = *(const bf16x8*)&sB[(SBOFS) + (wn * 32 + tn * 16 + ln) * LDP + kk * 32 + quad * 8]; \
        _Pragma("unroll")                                                    \
        for (int tm = 0; tm < 2; ++tm)                                       \
            _Pragma("unroll")                                                \
            for (int tn = 0; tn < 2; ++tn)                                   \
                acc[tm][tn] = __builtin_amdgcn_mfma_f32_16x16x32_bf16(afr[tm], bfr[tn], acc[tm][tn], 0, 0, 0); \
    }

__global__ __launch_bounds__(256, 4) void gemm_b_kernel(const bf16_t* __restrict__ T0,
                                                        const bf16_t* __restrict__ T1,
                                                        const bf16_t* __restrict__ T2,
                                                        const bf16_t* __restrict__ T3,
                                                        const bf16_t* __restrict__ Wb,
                                                        float* __restrict__ out) {
    __shared__ __align__(16) bf16_t sA[2 * 64 * LDP];   // 18.4 KB
    __shared__ __align__(16) bf16_t sB[2 * 64 * LDP];   // 18.4 KB

    const int bid = blockIdx.x;     // 0..1023
    const int ib = bid >> 4;        // 0..63
    const int nb = bid & 15;        // 0..15
    const int i0 = ib * 64;
    const int n0 = nb * 64;

    const int tid  = threadIdx.x;
    const int wave = tid >> 6;
    const int lane = tid & 63;
    const int quad = lane >> 4;
    const int ln   = lane & 15;
    const int wm   = wave >> 1;     // 0..1 over 64 m
    const int wn   = wave & 1;      // 0..1 over 64 n
    const int srow = tid >> 3;      // 0..31
    const int kc8  = (tid & 7) * 8;

    f32x4 acc[2][2];
#pragma unroll
    for (int a = 0; a < 2; ++a)
#pragma unroll
        for (int b = 0; b < 2; ++b) acc[a][b] = (f32x4){0, 0, 0, 0};

    const int nsteps = DEMB / 64;   // 16 (even)

    const bf16_t* p0[2];
    const bf16_t* p1[2];
    const bf16_t* p2[2];
    const bf16_t* p3[2];
    const bf16_t* pW[2];
    bf16x8 ra0[2], rb0[2], ra1[2], rb1[2];
#pragma unroll
    for (int c = 0; c < 2; ++c) {
        size_t arow = (size_t)(i0 + c * 32 + srow) * DEMB + kc8;
        p0[c] = T0 + arow;
        p1[c] = T1 + arow;
        p2[c] = T2 + arow;
        p3[c] = T3 + arow;
        pW[c] = Wb + (size_t)(n0 + c * 32 + srow) * DEMB + kc8;
    }

    GB_PREFETCH(ra0, rb0)   // step 0
    GB_PREFETCH(ra1, rb1)   // step 1

    for (int s = 0;; s += 2) {
        GB_STAGE(0, ra0, rb0)
        __syncthreads();
        if (s + 2 < nsteps) { GB_PREFETCH(ra0, rb0) }
        GB_COMPUTE(0)
        GB_STAGE(64 * LDP, ra1, rb1)
        __syncthreads();
        if (s + 3 < nsteps) { GB_PREFETCH(ra1, rb1) }
        GB_COMPUTE(64 * LDP)
        if (s + 2 >= nsteps) break;
    }

#pragma unroll
    for (int tm = 0; tm < 2; ++tm) {
        int row_base = i0 + wm * 32 + tm * 16 + quad * 4;
#pragma unroll
        for (int tn = 0; tn < 2; ++tn) {
            int col = n0 + wn * 32 + tn * 16 + ln;
#pragma unroll
            for (int r = 0; r < 4; ++r)
                out[(size_t)(row_base + r) * DV + col] = acc[tm][tn][r];
        }
    }
}

// ---------------------------------------------------------------------------
extern "C" void kernel_launch(void* const* d_in, const int* in_sizes, int n_in,
                              void* d_out, int out_size, void* d_ws, size_t ws_size,
                              hipStream_t stream) {
    const float* E = (const float*)d_in[0];   // (1024, 4096) f32
    const float* W = (const float*)d_in[1];   // (1024, 1024) f32
    float* out = (float*)d_out;               // (4096, 1024) f32

    char* ws = (char*)d_ws;
    bf16_t* Eb = (bf16_t*)(ws);                               // 8 MB
    bf16_t* T0 = (bf16_t*)(ws + (size_t)8  * 1024 * 1024);    // 8 MB
    bf16_t* T1 = (bf16_t*)(ws + (size_t)16 * 1024 * 1024);    // 8 MB
    bf16_t* T2 = (bf16_t*)(ws + (size_t)24 * 1024 * 1024);    // 8 MB
    bf16_t* T3 = (bf16_t*)(ws + (size_t)32 * 1024 * 1024);    // 8 MB
    bf16_t* Wb = (bf16_t*)(ws + (size_t)40 * 1024 * 1024);    // 2 MB
    bf16_t* R  = (bf16_t*)(ws + (size_t)42 * 1024 * 1024);    // 68.6 KB

    prep_kernel<<<2694, 256, 0, stream>>>(E, W, Eb, Wb, R);
    gemm_a_kernel<<<1024, 256, 0, stream>>>(R, Eb, T0, T1, T2, T3);
    gemm_b_kernel<<<1024, 256, 0, stream>>>(T0, T1, T2, T3, Wb, out);
}